// Round 1
// baseline (2067.241 us; speedup 1.0000x reference)
//
#include <hip/hip_runtime.h>
#include <hip/hip_bf16.h>
#include <cstdint>

// Problem constants
#define B_     2
#define N_     100000
#define C_     256
#define H_     8
#define D_     64
#define S_     64
#define INNER_ 512

#define TILE_T 64
#define NTILES ((N_ + TILE_T - 1) / TILE_T)   // 1563 (last tile has 32 valid tokens)
#define PBLK   96                             // partitions per (b,h); grid = 96*8*2 = 1536 blocks

// Workspace layout (floats)
#define OFF_WEFF 0                              // [H][C][S]  = 131072
#define OFF_WFX  (H_*C_*S_)                     // [H][C][D]  = 131072
#define OFF_BIAS (OFF_WFX + H_*C_*D_)           // [H][S]     = 512
#define OFF_ACC  (OFF_BIAS + H_*S_)             // [B][H][S][D] = 65536
#define OFF_NRM  (OFF_ACC + B_*H_*S_*D_)        // [B][H][S]  = 1024
#define WS_FLOATS (OFF_NRM + B_*H_*S_)          // 329216 floats = ~1.26 MB

// ---------------------------------------------------------------------------
// K0: precompute W_eff[h][c][s] = sum_d W_x[c, h*D+d] * W_slice[d, s]
//     repack  W_fx  -> wfx[h][c][d]
//     bias_eff[h][s] = sum_d b_x[h*D+d]*W_slice[d,s] + b_slice[s]
// ---------------------------------------------------------------------------
__global__ void prep_kernel(const float* __restrict__ W_x,
                            const float* __restrict__ b_x,
                            const float* __restrict__ W_fx,
                            const float* __restrict__ W_slice,
                            const float* __restrict__ b_slice,
                            float* __restrict__ ws) {
    int id = blockIdx.x * blockDim.x + threadIdx.x;   // H*C*16 = 32768 threads
    int sq = id & 15;              // s-quad
    int c  = (id >> 4) & (C_ - 1);
    int h  = id >> 12;             // id / 4096

    float a0 = 0.f, a1 = 0.f, a2 = 0.f, a3 = 0.f;
    #pragma unroll 8
    for (int d = 0; d < D_; ++d) {
        float a = W_x[c * INNER_ + h * D_ + d];
        const float* wsl = W_slice + d * S_ + sq * 4;
        a0 = fmaf(a, wsl[0], a0);
        a1 = fmaf(a, wsl[1], a1);
        a2 = fmaf(a, wsl[2], a2);
        a3 = fmaf(a, wsl[3], a3);
    }
    float* weff = ws + OFF_WEFF + (h * C_ + c) * S_ + sq * 4;
    weff[0] = a0; weff[1] = a1; weff[2] = a2; weff[3] = a3;

    // repack W_fx (pure transpose per head; contiguous in d already)
    const float* src = W_fx + c * INNER_ + h * D_ + sq * 4;
    float* dst = ws + OFF_WFX + (h * C_ + c) * D_ + sq * 4;
    dst[0] = src[0]; dst[1] = src[1]; dst[2] = src[2]; dst[3] = src[3];

    if (c == 0) {
        float b0 = 0.f, b1 = 0.f, b2 = 0.f, b3 = 0.f;
        #pragma unroll 8
        for (int d = 0; d < D_; ++d) {
            float a = b_x[h * D_ + d];
            const float* wsl = W_slice + d * S_ + sq * 4;
            b0 = fmaf(a, wsl[0], b0);
            b1 = fmaf(a, wsl[1], b1);
            b2 = fmaf(a, wsl[2], b2);
            b3 = fmaf(a, wsl[3], b3);
        }
        float* be = ws + OFF_BIAS + h * S_ + sq * 4;
        be[0] = b0 + b_slice[sq * 4 + 0];
        be[1] = b1 + b_slice[sq * 4 + 1];
        be[2] = b2 + b_slice[sq * 4 + 2];
        be[3] = b3 + b_slice[sq * 4 + 3];
    }
}

// ---------------------------------------------------------------------------
// K1: fused main kernel. Block handles (b, h, partition p).
//   For each 64-token tile:
//     stage x chunk (64 tok x 64 k) in LDS transposed,
//     GEMM -> logits (64x64) + fx (64x64) in registers,
//     wave-per-token softmax over S=64 lanes,
//     accumulation GEMM  accO[s][d] += sum_t w[t][s]*fx[t][d] (persistent regs)
//   Flush via atomicAdd into ws accumulators.
// ---------------------------------------------------------------------------
__global__ __launch_bounds__(256, 2) void main_kernel(
        const float* __restrict__ x,
        const float* __restrict__ b_fx,
        const float* __restrict__ temperature,
        float* __restrict__ ws) {
    __shared__ float xs[64 * 65];   // [k_local][token], stride 65 (bank-safe)
    __shared__ float ls[64 * 68];   // [token][s], stride 68 (float4-aligned)
    __shared__ float fs[64 * 68];   // [token][d]
    __shared__ float nsh[4 * 64];

    const int tid = threadIdx.x;
    const int p = blockIdx.x, h = blockIdx.y, b = blockIdx.z;
    const int tr = tid >> 4, cr = tid & 15;   // 16x16 thread grid
    const int lane = tid & 63, wv = tid >> 6;

    const float* xb   = x + (size_t)b * ((size_t)N_ * C_);
    const float* weff = ws + OFF_WEFF + h * (C_ * S_);
    const float* wfx  = ws + OFF_WFX  + h * (C_ * D_);
    const float* bias = ws + OFF_BIAS + h * S_;

    float tval = temperature[h];
    tval = fminf(fmaxf(tval, 0.1f), 5.0f);
    const float invt = 1.0f / tval;

    float bl[4], bf[4];
    #pragma unroll
    for (int j = 0; j < 4; ++j) {
        bl[j] = bias[cr * 4 + j];
        bf[j] = b_fx[h * D_ + cr * 4 + j];
    }

    float accO[4][4] = {};
    float nrm = 0.f;

    for (int tile = p; tile < NTILES; tile += PBLK) {
        const int t0 = tile * TILE_T;
        float accL[4][4] = {};
        float accF[4][4] = {};

        for (int kc = 0; kc < 4; ++kc) {
            __syncthreads();   // protects xs restage AND ls/fs reuse across tiles
            // stage: 64 tok x 64 k chunk, transposed into xs[k][t]
            {
                const int c4 = cr * 4;
                #pragma unroll
                for (int it = 0; it < 4; ++it) {
                    int t = tr + it * 16;
                    int gt = t0 + t;
                    float4 v = make_float4(0.f, 0.f, 0.f, 0.f);
                    if (gt < N_)
                        v = *(const float4*)(xb + (size_t)gt * C_ + kc * 64 + c4);
                    xs[(c4 + 0) * 65 + t] = v.x;
                    xs[(c4 + 1) * 65 + t] = v.y;
                    xs[(c4 + 2) * 65 + t] = v.z;
                    xs[(c4 + 3) * 65 + t] = v.w;
                }
            }
            __syncthreads();

            const float* wl_base = weff + (kc * 64) * S_ + cr * 4;
            const float* wf_base = wfx  + (kc * 64) * D_ + cr * 4;
            #pragma unroll 4
            for (int kk = 0; kk < 64; ++kk) {
                float av[4];
                #pragma unroll
                for (int i = 0; i < 4; ++i) av[i] = xs[kk * 65 + tr * 4 + i];
                float4 wl = *(const float4*)(wl_base + kk * S_);
                float4 wf = *(const float4*)(wf_base + kk * D_);
                float wlv[4] = {wl.x, wl.y, wl.z, wl.w};
                float wfv[4] = {wf.x, wf.y, wf.z, wf.w};
                #pragma unroll
                for (int i = 0; i < 4; ++i) {
                    #pragma unroll
                    for (int j = 0; j < 4; ++j) {
                        accL[i][j] = fmaf(av[i], wlv[j], accL[i][j]);
                        accF[i][j] = fmaf(av[i], wfv[j], accF[i][j]);
                    }
                }
            }
        }

        // epilogue: write scaled logits and fx to LDS
        #pragma unroll
        for (int i = 0; i < 4; ++i) {
            float4 vl, vf;
            vl.x = (accL[i][0] + bl[0]) * invt;
            vl.y = (accL[i][1] + bl[1]) * invt;
            vl.z = (accL[i][2] + bl[2]) * invt;
            vl.w = (accL[i][3] + bl[3]) * invt;
            vf.x = accF[i][0] + bf[0];
            vf.y = accF[i][1] + bf[1];
            vf.z = accF[i][2] + bf[2];
            vf.w = accF[i][3] + bf[3];
            *(float4*)(ls + (tr * 4 + i) * 68 + cr * 4) = vl;
            *(float4*)(fs + (tr * 4 + i) * 68 + cr * 4) = vf;
        }
        __syncthreads();

        // softmax: wave wv owns tokens wv*16 .. wv*16+15; lane = s
        #pragma unroll 1
        for (int tt = 0; tt < 16; ++tt) {
            int t = wv * 16 + tt;
            float lg = ls[t * 68 + lane];
            float m = lg;
            #pragma unroll
            for (int off = 32; off > 0; off >>= 1)
                m = fmaxf(m, __shfl_xor(m, off, 64));
            float e = __expf(lg - m);
            float ssum = e;
            #pragma unroll
            for (int off = 32; off > 0; off >>= 1)
                ssum += __shfl_xor(ssum, off, 64);
            float w = e / ssum;
            if (t0 + t >= N_) w = 0.f;   // zero out padded tokens
            nrm += w;
            ls[t * 68 + lane] = w;
        }
        __syncthreads();

        // accumulation GEMM: accO[i][j] += sum_t w[t][sr*4+i] * fx[t][dr*4+j]
        {
            const int sr = tr, dr = cr;
            #pragma unroll 4
            for (int t = 0; t < 64; ++t) {
                float wv4[4];
                #pragma unroll
                for (int i = 0; i < 4; ++i) wv4[i] = ls[t * 68 + sr * 4 + i];
                float4 f = *(const float4*)(fs + t * 68 + dr * 4);
                float fv[4] = {f.x, f.y, f.z, f.w};
                #pragma unroll
                for (int i = 0; i < 4; ++i) {
                    #pragma unroll
                    for (int j = 0; j < 4; ++j)
                        accO[i][j] = fmaf(wv4[i], fv[j], accO[i][j]);
                }
            }
        }
    }

    // flush partial slice_token
    float* accg = ws + OFF_ACC + (size_t)((b * H_ + h) * S_) * D_;
    #pragma unroll
    for (int i = 0; i < 4; ++i) {
        #pragma unroll
        for (int j = 0; j < 4; ++j)
            atomicAdd(accg + (tr * 4 + i) * D_ + cr * 4 + j, accO[i][j]);
    }
    // flush norm
    nsh[wv * 64 + lane] = nrm;
    __syncthreads();
    if (tid < 64) {
        float tot = nsh[tid] + nsh[64 + tid] + nsh[128 + tid] + nsh[192 + tid];
        atomicAdd(ws + OFF_NRM + (b * H_ + h) * S_ + tid, tot);
    }
}

// ---------------------------------------------------------------------------
// K2: finalize out[b,h,s,d] = acc / (norm + 1e-5)
// ---------------------------------------------------------------------------
__global__ void finalize_kernel(const float* __restrict__ ws, float* __restrict__ out) {
    int idx = blockIdx.x * blockDim.x + threadIdx.x;   // 65536 total
    float a = ws[OFF_ACC + idx];
    float n = ws[OFF_NRM + idx / D_];
    out[idx] = a / (n + 1e-5f);
}

// ---------------------------------------------------------------------------
extern "C" void kernel_launch(void* const* d_in, const int* in_sizes, int n_in,
                              void* d_out, int out_size, void* d_ws, size_t ws_size,
                              hipStream_t stream) {
    const float* x           = (const float*)d_in[0];
    const float* W_x         = (const float*)d_in[1];
    const float* b_x         = (const float*)d_in[2];
    const float* W_fx        = (const float*)d_in[3];
    const float* b_fx        = (const float*)d_in[4];
    const float* W_slice     = (const float*)d_in[5];
    const float* b_slice     = (const float*)d_in[6];
    const float* temperature = (const float*)d_in[7];
    float* out = (float*)d_out;
    float* ws  = (float*)d_ws;

    // zero the accumulators (ws is re-poisoned to 0xAA before every launch)
    hipMemsetAsync(ws + OFF_ACC, 0,
                   (size_t)(B_ * H_ * S_ * D_ + B_ * H_ * S_) * sizeof(float), stream);

    prep_kernel<<<dim3((H_ * C_ * 16) / 256), dim3(256), 0, stream>>>(
        W_x, b_x, W_fx, W_slice, b_slice, ws);

    dim3 grid(PBLK, H_, B_);
    main_kernel<<<grid, dim3(256), 0, stream>>>(x, b_fx, temperature, ws);

    finalize_kernel<<<dim3((B_ * H_ * S_ * D_) / 256), dim3(256), 0, stream>>>(ws, out);
}

// Round 2
// 663.759 us; speedup vs baseline: 3.1144x; 3.1144x over previous
//
#include <hip/hip_runtime.h>
#include <hip/hip_bf16.h>
#include <cstdint>

// Problem constants
#define B_     2
#define N_     100000
#define C_     256
#define H_     8
#define D_     64
#define S_     64
#define INNER_ 512

#define TILE_T 64
#define NTILES ((N_ + TILE_T - 1) / TILE_T)   // 1563
#define PBLK   32                             // grid = 32*8*2 = 512 blocks = 2/CU resident

// Workspace layout (bytes)
#define WEFFT_OFF 0                           // bf16 [H][S][C]   = 262144 B
#define WFXT_OFF  262144                      // bf16 [H][D][C]   = 262144 B
#define BIASE_OFF 524288                      // f32  [H][S]      = 2048 B
#define ACC_OFF   526336                      // f32  [B][H][S][D]= 262144 B
#define NRM_OFF   788480                      // f32  [B][H][S]   = 4096 B
#define WS_END    792576

typedef __attribute__((ext_vector_type(8))) short short8;
typedef __attribute__((ext_vector_type(4))) float f32x4;

__device__ inline short f2bf(float f) {
    __hip_bfloat16 h = __float2bfloat16(f);
    short s; __builtin_memcpy(&s, &h, 2); return s;
}
__device__ inline uint32_t pk2(float a, float b) {
    __hip_bfloat162 h = __float22bfloat162_rn(float2{a, b});
    uint32_t u; __builtin_memcpy(&u, &h, 4); return u;
}

// ---------------------------------------------------------------------------
// prep: weffT[h][s][k] = sum_d W_x[k][h*64+d]*W_slice[d][s]  (bf16, [s][k] k-contig)
//       wfxT[h][d][k]  = W_fx[k][h*64+d]                     (bf16)
//       biasE[h][s]    = sum_d b_x[h*64+d]*W_slice[d][s] + b_slice[s]  (f32)
// ---------------------------------------------------------------------------
__global__ void prep_kernel(const float* __restrict__ W_x,
                            const float* __restrict__ b_x,
                            const float* __restrict__ W_fx,
                            const float* __restrict__ W_slice,
                            const float* __restrict__ b_slice,
                            uint8_t* __restrict__ wsb) {
    int id = blockIdx.x * 256 + threadIdx.x;
    const int NW = H_ * S_ * C_;              // 131072
    if (id < NW) {
        // k inner: s wave-uniform -> W_slice scalar loads; W_x L1-resident
        int k = id & 255, s = (id >> 8) & 63, h = id >> 14;
        float a = 0.f;
        #pragma unroll 8
        for (int d = 0; d < D_; ++d)
            a = fmaf(W_x[k * INNER_ + h * 64 + d], W_slice[d * 64 + s], a);
        ((short*)(wsb + WEFFT_OFF))[(h * 64 + s) * 256 + k] = f2bf(a);
    } else if (id < 2 * NW) {
        int j = id - NW;
        int k = j & 255, d = (j >> 8) & 63, h = j >> 14;
        ((short*)(wsb + WFXT_OFF))[(h * 64 + d) * 256 + k] =
            f2bf(W_fx[k * INNER_ + h * 64 + d]);
    } else if (id < 2 * NW + H_ * S_) {
        int j = id - 2 * NW;
        int s = j & 63, h = j >> 6;
        float a = 0.f;
        #pragma unroll 8
        for (int d = 0; d < D_; ++d)
            a = fmaf(b_x[h * 64 + d], W_slice[d * 64 + s], a);
        ((float*)(wsb + BIASE_OFF))[h * 64 + s] = a + b_slice[s];
    }
}

// ---------------------------------------------------------------------------
// main: block = (partition, h, b); 4 waves: wave = (g = GEMM sel, nh = n-half)
//   g=0 waves compute logits (n = s), g=1 waves compute fx (n = d).
//   Weights live in registers as persistent MFMA B-frags (loaded once).
//   Per 64-token tile: stage x bf16 -> LDS; MFMA K-loop; cross-wave softmax;
//   w,fx -> LDS bf16; aggregation MFMA into persistent accO; atomic flush.
// ---------------------------------------------------------------------------
__global__ __launch_bounds__(256, 2) void main_kernel(
        const float* __restrict__ x,
        const float* __restrict__ b_fx,
        const float* __restrict__ temperature,
        const uint8_t* __restrict__ wsb,
        float* __restrict__ accg,
        float* __restrict__ nrmg) {
    __shared__ short xs[TILE_T * 264];        // [tok][k] bf16, pad->264 (33792 B)
    __shared__ short wsl[S_ * 72];            // [s][t]  bf16 weights (9216 B)
    __shared__ short fsl[D_ * 72];            // [d][t]  bf16 fx      (9216 B)
    __shared__ float smA[2 * TILE_T];         // cross-wave max exchange
    __shared__ float smB[2 * TILE_T];         // cross-wave sum exchange

    const int tid  = threadIdx.x;
    const int p = blockIdx.x, h = blockIdx.y, b = blockIdx.z;
    const int lane = tid & 63, wv = tid >> 6;
    const int l = lane & 15, q = lane >> 4;
    const int g = wv & 1, nh = wv >> 1;

    // persistent B-frags: my GEMM's weights, n in [nh*32, nh*32+32)
    const short* wT = (const short*)(wsb + (g ? WFXT_OFF : WEFFT_OFF)) + h * (64 * 256);
    short8 breg[2][8];
    #pragma unroll
    for (int nt = 0; nt < 2; ++nt)
        #pragma unroll
        for (int k = 0; k < 8; ++k)
            breg[nt][k] = *(const short8*)(wT + (nh * 32 + nt * 16 + l) * 256 + k * 32 + q * 8);

    float invt; { float t = temperature[h]; t = fminf(fmaxf(t, 0.1f), 5.0f); invt = 1.f / t; }
    float bias_n[2];
    #pragma unroll
    for (int nt = 0; nt < 2; ++nt) {
        int n = nh * 32 + nt * 16 + l;
        bias_n[nt] = g ? b_fx[h * 64 + n] : ((const float*)(wsb + BIASE_OFF))[h * 64 + n];
    }

    const float* xb = x + (size_t)b * ((size_t)N_ * C_);
    f32x4 accO[4] = {};                       // out strip [16 s][64 d], persistent
    float nrmacc[2] = {0.f, 0.f};

    for (int tile = p; tile < NTILES; tile += PBLK) {
        const int t0 = tile * TILE_T;
        __syncthreads();                      // B1: prev tile's xs/wsl/fsl reads done

        // ---- stage x tile -> bf16 LDS (thread: tok = tid&63, k-quarter = tid>>6)
        {
            int tok = tid & 63, kq = tid >> 6;
            int gt = t0 + tok;
            const float* src = xb + (size_t)gt * C_ + kq * 64;
            short* dst = xs + tok * 264 + kq * 64;
            if (gt < N_) {
                #pragma unroll
                for (int i = 0; i < 8; ++i) {
                    float4 f0 = *(const float4*)(src + i * 8);
                    float4 f1 = *(const float4*)(src + i * 8 + 4);
                    uint32_t u[4] = { pk2(f0.x, f0.y), pk2(f0.z, f0.w),
                                      pk2(f1.x, f1.y), pk2(f1.z, f1.w) };
                    *(int4*)(dst + i * 8) = *(int4*)u;
                }
            } else {
                int4 z = make_int4(0, 0, 0, 0);
                #pragma unroll
                for (int i = 0; i < 8; ++i) *(int4*)(dst + i * 8) = z;
            }
        }
        __syncthreads();                      // B2: xs ready

        // ---- main MFMA GEMM: acc[m][nt] = x_tile @ W  (m = 16-token strip)
        f32x4 acc[4][2] = {};
        #pragma unroll
        for (int k = 0; k < 8; ++k) {
            short8 a[4];
            #pragma unroll
            for (int m = 0; m < 4; ++m)
                a[m] = *(const short8*)(xs + (m * 16 + l) * 264 + k * 32 + q * 8);
            #pragma unroll
            for (int m = 0; m < 4; ++m)
                #pragma unroll
                for (int nt = 0; nt < 2; ++nt)
                    acc[m][nt] = __builtin_amdgcn_mfma_f32_16x16x32_bf16(
                        a[m], breg[nt][k], acc[m][nt], 0, 0, 0);
        }

        float pm[4][4], ps[4][4];
        if (g == 0) {
            // logits: add bias, scale by 1/temp; partial max over my 32 s
            #pragma unroll
            for (int m = 0; m < 4; ++m)
                #pragma unroll
                for (int nt = 0; nt < 2; ++nt)
                    #pragma unroll
                    for (int r = 0; r < 4; ++r)
                        acc[m][nt][r] = (acc[m][nt][r] + bias_n[nt]) * invt;
            #pragma unroll
            for (int m = 0; m < 4; ++m)
                #pragma unroll
                for (int r = 0; r < 4; ++r) {
                    float v = fmaxf(acc[m][0][r], acc[m][1][r]);
                    v = fmaxf(v, __shfl_xor(v, 1, 64));
                    v = fmaxf(v, __shfl_xor(v, 2, 64));
                    v = fmaxf(v, __shfl_xor(v, 4, 64));
                    v = fmaxf(v, __shfl_xor(v, 8, 64));
                    pm[m][r] = v;
                }
            if (l == 0)
                #pragma unroll
                for (int m = 0; m < 4; ++m)
                    #pragma unroll
                    for (int r = 0; r < 4; ++r)
                        smA[nh * 64 + m * 16 + q * 4 + r] = pm[m][r];
        } else {
            // fx: add bias, convert, store to fsl[d][t]
            #pragma unroll
            for (int m = 0; m < 4; ++m)
                #pragma unroll
                for (int nt = 0; nt < 2; ++nt) {
                    int dd = nh * 32 + nt * 16 + l, tt = m * 16 + q * 4;
                    *(uint32_t*)(fsl + dd * 72 + tt) =
                        pk2(acc[m][nt][0] + bias_n[nt], acc[m][nt][1] + bias_n[nt]);
                    *(uint32_t*)(fsl + dd * 72 + tt + 2) =
                        pk2(acc[m][nt][2] + bias_n[nt], acc[m][nt][3] + bias_n[nt]);
                }
        }
        __syncthreads();                      // B3: smA (+fsl) ready

        if (g == 0) {
            #pragma unroll
            for (int m = 0; m < 4; ++m)
                #pragma unroll
                for (int r = 0; r < 4; ++r) {
                    float Mx = fmaxf(pm[m][r], smA[(1 - nh) * 64 + m * 16 + q * 4 + r]);
                    acc[m][0][r] = __expf(acc[m][0][r] - Mx);
                    acc[m][1][r] = __expf(acc[m][1][r] - Mx);
                    float sv = acc[m][0][r] + acc[m][1][r];
                    sv += __shfl_xor(sv, 1, 64);
                    sv += __shfl_xor(sv, 2, 64);
                    sv += __shfl_xor(sv, 4, 64);
                    sv += __shfl_xor(sv, 8, 64);
                    ps[m][r] = sv;
                }
            if (l == 0)
                #pragma unroll
                for (int m = 0; m < 4; ++m)
                    #pragma unroll
                    for (int r = 0; r < 4; ++r)
                        smB[nh * 64 + m * 16 + q * 4 + r] = ps[m][r];
        }
        __syncthreads();                      // B4: smB ready

        if (g == 0) {
            #pragma unroll
            for (int m = 0; m < 4; ++m) {
                #pragma unroll
                for (int r = 0; r < 4; ++r) {
                    float Sv = ps[m][r] + smB[(1 - nh) * 64 + m * 16 + q * 4 + r];
                    float rs = __builtin_amdgcn_rcpf(Sv);
                    int gt = t0 + m * 16 + q * 4 + r;
                    float w0 = acc[m][0][r] * rs, w1 = acc[m][1][r] * rs;
                    if (gt >= N_) { w0 = 0.f; w1 = 0.f; }
                    acc[m][0][r] = w0; acc[m][1][r] = w1;
                    nrmacc[0] += w0; nrmacc[1] += w1;
                }
                #pragma unroll
                for (int nt = 0; nt < 2; ++nt) {
                    int ss = nh * 32 + nt * 16 + l, tt = m * 16 + q * 4;
                    *(uint32_t*)(wsl + ss * 72 + tt)     = pk2(acc[m][nt][0], acc[m][nt][1]);
                    *(uint32_t*)(wsl + ss * 72 + tt + 2) = pk2(acc[m][nt][2], acc[m][nt][3]);
                }
            }
        }
        __syncthreads();                      // B5: wsl/fsl ready

        // ---- aggregation MFMA: accO[s-strip=wv][d] += w^T @ fx  (K = 64 tokens)
        #pragma unroll
        for (int kk = 0; kk < 2; ++kk) {
            short8 aw = *(const short8*)(wsl + (wv * 16 + l) * 72 + kk * 32 + q * 8);
            #pragma unroll
            for (int nt = 0; nt < 4; ++nt) {
                short8 bf = *(const short8*)(fsl + (nt * 16 + l) * 72 + kk * 32 + q * 8);
                accO[nt] = __builtin_amdgcn_mfma_f32_16x16x32_bf16(aw, bf, accO[nt], 0, 0, 0);
            }
        }
    }

    // ---- flush
    float* ag = accg + (size_t)((b * H_ + h) * 64) * 64;
    #pragma unroll
    for (int nt = 0; nt < 4; ++nt)
        #pragma unroll
        for (int r = 0; r < 4; ++r)
            atomicAdd(ag + (wv * 16 + q * 4 + r) * 64 + nt * 16 + l, accO[nt][r]);
    if (g == 0) {
        #pragma unroll
        for (int nt = 0; nt < 2; ++nt) {
            float v = nrmacc[nt];
            v += __shfl_xor(v, 16, 64);
            v += __shfl_xor(v, 32, 64);
            if (lane < 16)
                atomicAdd(nrmg + (b * H_ + h) * 64 + nh * 32 + nt * 16 + lane, v);
        }
    }
}

// ---------------------------------------------------------------------------
__global__ void finalize_kernel(const uint8_t* __restrict__ wsb, float* __restrict__ out) {
    int idx = blockIdx.x * blockDim.x + threadIdx.x;   // 65536
    float a = ((const float*)(wsb + ACC_OFF))[idx];
    float n = ((const float*)(wsb + NRM_OFF))[idx / D_];
    out[idx] = a / (n + 1e-5f);
}

// ---------------------------------------------------------------------------
extern "C" void kernel_launch(void* const* d_in, const int* in_sizes, int n_in,
                              void* d_out, int out_size, void* d_ws, size_t ws_size,
                              hipStream_t stream) {
    const float* x           = (const float*)d_in[0];
    const float* W_x         = (const float*)d_in[1];
    const float* b_x         = (const float*)d_in[2];
    const float* W_fx        = (const float*)d_in[3];
    const float* b_fx        = (const float*)d_in[4];
    const float* W_slice     = (const float*)d_in[5];
    const float* b_slice     = (const float*)d_in[6];
    const float* temperature = (const float*)d_in[7];
    float* out = (float*)d_out;
    uint8_t* wsb = (uint8_t*)d_ws;

    hipMemsetAsync(wsb + ACC_OFF, 0, (NRM_OFF - ACC_OFF) + B_ * H_ * S_ * 4, stream);

    int prep_threads = 2 * H_ * S_ * C_ + H_ * S_;
    prep_kernel<<<dim3((prep_threads + 255) / 256), dim3(256), 0, stream>>>(
        W_x, b_x, W_fx, W_slice, b_slice, wsb);

    main_kernel<<<dim3(PBLK, H_, B_), dim3(256), 0, stream>>>(
        x, b_fx, temperature, wsb,
        (float*)(wsb + ACC_OFF), (float*)(wsb + NRM_OFF));

    finalize_kernel<<<dim3((B_ * H_ * S_ * D_) / 256), dim3(256), 0, stream>>>(wsb, out);
}